// Round 1
// baseline (151.017 us; speedup 1.0000x reference)
//
#include <hip/hip_runtime.h>
#include <hip/hip_bf16.h>
#include <stdint.h>

typedef __hip_bfloat16 bf16;
typedef __attribute__((ext_vector_type(8))) short bf16x8;
typedef __attribute__((ext_vector_type(4))) float f32x4;

#define MFMA16(a, b, c) __builtin_amdgcn_mfma_f32_16x16x32_bf16(a, b, c, 0, 0, 0)

__device__ __forceinline__ void gl_lds16(const void* g, void* l) {
  __builtin_amdgcn_global_load_lds(
      (const __attribute__((address_space(1))) uint32_t*)g,
      (__attribute__((address_space(3))) uint32_t*)l, 16, 0, 0);
}

// ---------------- cast fp32 -> bf16 (vectorized) ----------------
struct alignas(8) bf16x4s { bf16 a, b, c, d; };

__global__ void k_cast(const float* __restrict__ src, bf16* __restrict__ dst, int n4) {
  int i = blockIdx.x * 256 + threadIdx.x;
  if (i >= n4) return;
  float4 v = ((const float4*)src)[i];
  bf16x4s o{__float2bfloat16(v.x), __float2bfloat16(v.y),
            __float2bfloat16(v.z), __float2bfloat16(v.w)};
  ((bf16x4s*)dst)[i] = o;
}

// ---------------- axial RoPE cos/sin table: [pos(1024)][pair(32)] ----------------
__global__ void k_cis(float* __restrict__ cosT, float* __restrict__ sinT) {
  int i = blockIdx.x * 256 + threadIdx.x;  // 32768
  int pos = i >> 5, p = i & 31;
  int j = p & 15;
  float t = (p < 16) ? (float)(pos & 31) : (float)(pos >> 5);  // t_x = l%32, t_y = l/32
  float f = powf(10000.0f, -(float)j / 16.0f);
  float ang = t * f;
  float sv, cv;
  sincosf(ang, &sv, &cv);
  cosT[i] = cv;
  sinT[i] = sv;
}

// ---------------- shared 128x128-tile GEMM mainloop (K=768, B^T layout) -------
// C = A(M x 768) * Bt(N x 768)^T ; 256 threads = 4 waves (2x2), 64x64 per wave.
__device__ __forceinline__ void gemm128_loop(const bf16* __restrict__ A,
                                             const bf16* __restrict__ Bt,
                                             int m0, int n0, bf16* ldsA, bf16* ldsB,
                                             f32x4 acc[4][4]) {
  const int tid = threadIdx.x;
  const int lane = tid & 63, w = tid >> 6;
  const int wm = w >> 1, wn = w & 1;
  const int lr = lane & 15, lg = lane >> 4;
  for (int kt = 0; kt < 768; kt += 32) {
#pragma unroll
    for (int c = 0; c < 2; ++c) {
      const int off = c * 4096 + w * 1024 + lane * 16;  // byte in 8KB tile [128][32]bf16
      const int row = off >> 6, colb = off & 63;
      gl_lds16((const char*)A + ((size_t)(m0 + row) * 768 + kt) * 2 + colb,
               (char*)ldsA + c * 4096 + w * 1024);
      gl_lds16((const char*)Bt + ((size_t)(n0 + row) * 768 + kt) * 2 + colb,
               (char*)ldsB + c * 4096 + w * 1024);
    }
    __syncthreads();
    bf16x8 af[4], bf_[4];
#pragma unroll
    for (int f = 0; f < 4; ++f) {
      af[f] = *(const bf16x8*)((const char*)ldsA + (wm * 64 + f * 16 + lr) * 64 + lg * 16);
      bf_[f] = *(const bf16x8*)((const char*)ldsB + (wn * 64 + f * 16 + lr) * 64 + lg * 16);
    }
#pragma unroll
    for (int fm = 0; fm < 4; ++fm)
#pragma unroll
      for (int fn = 0; fn < 4; ++fn)
        acc[fm][fn] = MFMA16(af[fm], bf_[fn], acc[fm][fn]);
    __syncthreads();
  }
}

// ---------------- QKV GEMM + bias + RoPE epilogue ----------------
// writes Qb,Kb: [bn][pos][d] bf16 (RoPE'd); VbT: [bn][d][pos] bf16 (transposed)
__global__ __launch_bounds__(256, 2) void k_qkv(
    const bf16* __restrict__ xb, const bf16* __restrict__ wb, const float* __restrict__ qkvb,
    const float* __restrict__ cosT, const float* __restrict__ sinT,
    bf16* __restrict__ Qb, bf16* __restrict__ Kb, bf16* __restrict__ VbT) {
  __shared__ __align__(16) bf16 ldsA[128 * 32];
  __shared__ __align__(16) bf16 ldsB[128 * 32];
  const int m0 = (blockIdx.x & 31) * 128, n0 = (blockIdx.x >> 5) * 128;
  f32x4 acc[4][4] = {};
  gemm128_loop(xb, wb, m0, n0, ldsA, ldsB, acc);
  const int lane = threadIdx.x & 63, w = threadIdx.x >> 6;
  const int wm = w >> 1, wn = w & 1, lr = lane & 15, lg = lane >> 4;
#pragma unroll
  for (int fm = 0; fm < 4; ++fm) {
#pragma unroll
    for (int fn = 0; fn < 4; ++fn) {
      const int n = n0 + wn * 64 + fn * 16 + lr;  // 0..2303
      const int sect = n / 768;                   // 0=q 1=k 2=v (uniform per wave)
      const int cn = n - sect * 768;
      const int head = cn >> 6, d = cn & 63;
      const float bias = qkvb[n];
      const int p = d >> 1;
#pragma unroll
      for (int r = 0; r < 4; ++r) {
        const int m = m0 + wm * 64 + fm * 16 + lg * 4 + r;
        const int bb = m >> 10, pos = m & 1023;
        float val = acc[fm][fn][r] + bias;
        const float partner = __shfl_xor(val, 1);  // pair channel (d^1) lives in lane^1
        if (sect < 2) {
          const float cv = cosT[pos * 32 + p], sv = sinT[pos * 32 + p];
          val = (d & 1) ? (val * cv + partner * sv) : (val * cv - partner * sv);
        }
        const bf16 o = __float2bfloat16(val);
        const size_t base = (size_t)(bb * 12 + head) * 65536;
        if (sect == 0)      Qb[base + (size_t)pos * 64 + d] = o;
        else if (sect == 1) Kb[base + (size_t)pos * 64 + d] = o;
        else                VbT[base + (size_t)d * 1024 + pos] = o;
      }
    }
  }
}

// ---------------- decomposed rel-pos bias tables ----------------
// relh[bn][l][kh] = sum_d q[bn][l][d] * rel_pos_h[qh-kh+31][d]   (l=(qh,qw))
// relw[bn][l][kw] = sum_d q[bn][l][d] * rel_pos_w[qw-kw+31][d]
__global__ void k_relbias(const bf16* __restrict__ Qb, const float* __restrict__ relph,
                          const float* __restrict__ relpw, float* __restrict__ relh,
                          float* __restrict__ relw) {
  __shared__ float Rloc[32 * 68];  // padded stride 68: 16B-aligned rows, conflict-light
  __shared__ float qloc[32 * 64];
  const int bid = blockIdx.x;      // 0..3071
  const bool isW = bid >= 1536;
  const int t2 = isW ? bid - 1536 : bid;
  const int bn = t2 >> 5, rc = t2 & 31;  // rc = qh (rel_h) or qw (rel_w)
  const float* __restrict__ relp = isW ? relpw : relph;
  const int tid = threadIdx.x;
  {
    const int kh = tid >> 3, d8 = (tid & 7) * 8;
    const float* src = relp + (size_t)(rc - kh + 31) * 64 + d8;
    float4 v0 = *(const float4*)src;
    float4 v1 = *(const float4*)(src + 4);
    float* dstp = &Rloc[kh * 68 + d8];
    *(float4*)dstp = v0;
    *(float4*)(dstp + 4) = v1;
  }
  {
    const int h = tid >> 3, d8 = (tid & 7) * 8;
    const int l = isW ? (h * 32 + rc) : (rc * 32 + h);
    const bf16* src = Qb + (size_t)bn * 65536 + (size_t)l * 64 + d8;
#pragma unroll
    for (int jj = 0; jj < 8; ++jj) qloc[h * 64 + d8 + jj] = __bfloat162float(src[jj]);
  }
  __syncthreads();
  float* __restrict__ dst = isW ? relw : relh;
#pragma unroll
  for (int i = 0; i < 4; ++i) {
    const int idx = i * 256 + tid;
    const int a = idx >> 5, kk = idx & 31;
    float s = 0.0f;
#pragma unroll
    for (int d = 0; d < 64; d += 4) {
      const float4 rv = *(const float4*)&Rloc[kk * 68 + d];
      const float4 qv = *(const float4*)&qloc[a * 64 + d];
      s += qv.x * rv.x + qv.y * rv.y + qv.z * rv.z + qv.w * rv.w;
    }
    const int l = isW ? (a * 32 + rc) : (rc * 32 + a);
    dst[(size_t)bn * 32768 + (size_t)l * 32 + kk] = s;
  }
}

// ---------------- flash attention: one block = (bn, 64-row q-tile) ----------------
__global__ __launch_bounds__(256, 2) void k_attn(
    const bf16* __restrict__ Qb, const bf16* __restrict__ Kb, const bf16* __restrict__ VbT,
    const float* __restrict__ relh, const float* __restrict__ relw, bf16* __restrict__ attno) {
  __shared__ __align__(16) bf16 Kt[64 * 64];      // [key][ch], XOR-swizzled rows
  __shared__ __align__(16) bf16 Vt[64 * 64];      // [d][key] (V^T), XOR-swizzled rows
  __shared__ __align__(16) float bH[64 * 33];     // rel_h slice, padded
  __shared__ __align__(16) bf16 Pl[4][16 * 64];   // per-wave P transpose buffer, swizzled
  const int blk = blockIdx.x;                     // 768 = 48 bn * 16 qtiles
  const int bn = blk >> 4, qt = blk & 15;
  const int b = bn / 12, head = bn - b * 12;
  const int tid = threadIdx.x;
  const int lane = tid & 63, w = tid >> 6;
  const int lr = lane & 15, lg = lane >> 4;
  const size_t qkvbase = (size_t)bn * 65536;

  {  // stage bias-H rows for this q-tile
    const int r = tid >> 2, q8 = (tid & 3) * 8;
    const float* src = relh + (size_t)bn * 32768 + (size_t)(qt * 64 + r) * 32 + q8;
#pragma unroll
    for (int jj = 0; jj < 8; ++jj) bH[r * 33 + q8 + jj] = src[jj];
  }
  const int qrow_g = qt * 64 + w * 16 + lr;
  float bw[2][4];  // bias-W values this lane will need: kw = s1*16 + lg*4 + r
  {
    const float* rw = relw + (size_t)bn * 32768 + (size_t)qrow_g * 32;
#pragma unroll
    for (int s1 = 0; s1 < 2; ++s1)
#pragma unroll
      for (int r = 0; r < 4; ++r) bw[s1][r] = rw[s1 * 16 + lg * 4 + r];
  }
  bf16x8 qf[2];  // Q fragment (B-operand of swapped QK^T), kept in regs
  {
    const char* qp = (const char*)(Qb + qkvbase + (size_t)qrow_g * 64);
    qf[0] = *(const bf16x8*)(qp + lg * 16);
    qf[1] = *(const bf16x8*)(qp + 64 + lg * 16);
  }
  f32x4 oacc[4] = {};  // D rows = q-rows (lg*4+r), cols = d (dblk*16+lr)
  float mrun = -1e30f, lrun = 0.0f;

  for (int kt = 0; kt < 16; ++kt) {
    // stage K-tile and V^T-tile, pre-swizzling the GLOBAL source (rule #21)
#pragma unroll
    for (int c = 0; c < 2; ++c) {
      const int off = c * 4096 + w * 1024 + lane * 16;
      const int row = off >> 7;
      const int loff = off ^ ((row & 7) << 4);
      gl_lds16((const char*)Kb + (qkvbase + (size_t)kt * 4096) * 2 + loff,
               (char*)Kt + c * 4096 + w * 1024);
      gl_lds16((const char*)VbT + (qkvbase + (size_t)row * 1024 + (size_t)kt * 64) * 2 + (loff & 127),
               (char*)Vt + c * 4096 + w * 1024);
    }
    __syncthreads();
    // swapped QK^T: S^T[key][qrow]; lane holds q-row lr, keys s*16 + lg*4 + r
    f32x4 sa[4];
    const int sw = (lr & 7) << 4;
#pragma unroll
    for (int s = 0; s < 4; ++s) {
      const int krow = s * 16 + lr;
      bf16x8 k0 = *(const bf16x8*)((const char*)Kt + ((krow * 128 + lg * 16) ^ sw));
      bf16x8 k1 = *(const bf16x8*)((const char*)Kt + ((krow * 128 + 64 + lg * 16) ^ sw));
      f32x4 z = {};
      z = MFMA16(k0, qf[0], z);
      z = MFMA16(k1, qf[1], z);
      sa[s] = z;
    }
    // scores = S*scale + rel_h[qrow][kh] + rel_w[qrow][kw]
    const float bh0 = bH[(w * 16 + lr) * 33 + 2 * kt];
    const float bh1 = bH[(w * 16 + lr) * 33 + 2 * kt + 1];
    float sc[16];
    float mt = -1e30f;
#pragma unroll
    for (int s = 0; s < 4; ++s) {
      const float bh = (s < 2) ? bh0 : bh1;
#pragma unroll
      for (int r = 0; r < 4; ++r) {
        const float v = sa[s][r] * 0.125f + bh + bw[s & 1][r];
        sc[s * 4 + r] = v;
        mt = fmaxf(mt, v);
      }
    }
    mt = fmaxf(mt, __shfl_xor(mt, 16));
    mt = fmaxf(mt, __shfl_xor(mt, 32));
    const float mnew = fmaxf(mrun, mt);
    const float alpha = __expf(mrun - mnew);
    float ps = 0.0f;
    short4 pk[4];
#pragma unroll
    for (int s = 0; s < 4; ++s) {
#pragma unroll
      for (int r = 0; r < 4; ++r) {
        const float p = __expf(sc[s * 4 + r] - mnew);
        ps += p;
        ((bf16*)&pk[s])[r] = __float2bfloat16(p);
      }
    }
    ps += __shfl_xor(ps, 16);
    ps += __shfl_xor(ps, 32);
    lrun = lrun * alpha + ps;
    mrun = mnew;
    // P -> LDS (transpose for PV A-operand), same XOR swizzle on write & read
#pragma unroll
    for (int s = 0; s < 4; ++s) {
      int byteoff = (lr * 128 + s * 32 + lg * 8) ^ sw;
      *(short4*)((char*)Pl[w] + byteoff) = pk[s];
    }
    // rescale running output by alpha (per D-row = q-row lg*4+r)
#pragma unroll
    for (int r = 0; r < 4; ++r) {
      const float ar = __shfl(alpha, lg * 4 + r);
#pragma unroll
      for (int dblk = 0; dblk < 4; ++dblk) oacc[dblk][r] *= ar;
    }
    asm volatile("s_waitcnt lgkmcnt(0)" ::: "memory");  // P writes visible to wave
    // PV: out += P(16 x 64keys) * V(64keys x 64d)
#pragma unroll
    for (int kh = 0; kh < 2; ++kh) {
      const int abyte = (lr * 128 + kh * 64 + lg * 16) ^ sw;
      const bf16x8 pa = *(const bf16x8*)((const char*)Pl[w] + abyte);
#pragma unroll
      for (int dblk = 0; dblk < 4; ++dblk) {
        const int vrow = dblk * 16 + lr;
        const bf16x8 vb = *(const bf16x8*)((const char*)Vt + ((vrow * 128 + kh * 64 + lg * 16) ^ sw));
        oacc[dblk] = MFMA16(pa, vb, oacc[dblk]);
      }
    }
    __syncthreads();
  }
  // normalize + store to (B, L, nh*hd) bf16 for proj GEMM
#pragma unroll
  for (int r = 0; r < 4; ++r) {
    const float lsum = __shfl(lrun, lg * 4 + r);
    const float inv = 1.0f / lsum;
    const int qg = qt * 64 + w * 16 + lg * 4 + r;
#pragma unroll
    for (int dblk = 0; dblk < 4; ++dblk) {
      attno[((size_t)b * 1024 + qg) * 768 + head * 64 + dblk * 16 + lr] =
          __float2bfloat16(oacc[dblk][r] * inv);
    }
  }
}

// ---------------- output projection GEMM + bias (fp32 out) ----------------
__global__ __launch_bounds__(256, 2) void k_proj(
    const bf16* __restrict__ attno, const bf16* __restrict__ pwb,
    const float* __restrict__ projb, float* __restrict__ out) {
  __shared__ __align__(16) bf16 ldsA[128 * 32];
  __shared__ __align__(16) bf16 ldsB[128 * 32];
  const int m0 = (blockIdx.x & 31) * 128, n0 = (blockIdx.x >> 5) * 128;
  f32x4 acc[4][4] = {};
  gemm128_loop(attno, pwb, m0, n0, ldsA, ldsB, acc);
  const int lane = threadIdx.x & 63, w = threadIdx.x >> 6;
  const int wm = w >> 1, wn = w & 1, lr = lane & 15, lg = lane >> 4;
#pragma unroll
  for (int fm = 0; fm < 4; ++fm) {
#pragma unroll
    for (int fn = 0; fn < 4; ++fn) {
      const int n = n0 + wn * 64 + fn * 16 + lr;
      const float bias = projb[n];
#pragma unroll
      for (int r = 0; r < 4; ++r) {
        const int m = m0 + wm * 64 + fm * 16 + lg * 4 + r;
        out[(size_t)m * 768 + n] = acc[fm][fn][r] + bias;
      }
    }
  }
}

// ---------------- launch ----------------
extern "C" void kernel_launch(void* const* d_in, const int* in_sizes, int n_in,
                              void* d_out, int out_size, void* d_ws, size_t ws_size,
                              hipStream_t stream) {
  const float* x     = (const float*)d_in[0];
  const float* qkvw  = (const float*)d_in[1];
  const float* qkvb  = (const float*)d_in[2];
  const float* projw = (const float*)d_in[3];
  const float* projb = (const float*)d_in[4];
  const float* relph = (const float*)d_in[5];
  const float* relpw = (const float*)d_in[6];
  float* out = (float*)d_out;
  char* ws = (char*)d_ws;

  bf16*  xb     = (bf16*)(ws);              // 6,291,456 B
  bf16*  wqkvb  = (bf16*)(ws + 6291456);    // 3,538,944
  bf16*  wprojb = (bf16*)(ws + 9830400);    // 1,179,648
  float* cosT   = (float*)(ws + 11010048);  // 131,072
  float* sinT   = (float*)(ws + 11141120);  // 131,072
  bf16*  Qb     = (bf16*)(ws + 11272192);   // 6,291,456
  bf16*  Kb     = (bf16*)(ws + 17563648);   // 6,291,456
  bf16*  VbT    = (bf16*)(ws + 23855104);   // 6,291,456
  float* relh   = (float*)(ws + 30146560);  // 6,291,456
  float* relw   = (float*)(ws + 36438016);  // 6,291,456
  bf16*  attno  = (bf16*)(ws + 42729472);   // 6,291,456 -> ends 49,020,928

  k_cast<<<3072, 256, 0, stream>>>(x, xb, 786432);
  k_cast<<<1728, 256, 0, stream>>>(qkvw, wqkvb, 442368);
  k_cast<<<576, 256, 0, stream>>>(projw, wprojb, 147456);
  k_cis<<<128, 256, 0, stream>>>(cosT, sinT);
  k_qkv<<<576, 256, 0, stream>>>(xb, wqkvb, qkvb, cosT, sinT, Qb, Kb, VbT);
  k_relbias<<<3072, 256, 0, stream>>>(Qb, relph, relpw, relh, relw);
  k_attn<<<768, 256, 0, stream>>>(Qb, Kb, VbT, relh, relw, attno);
  k_proj<<<192, 256, 0, stream>>>(attno, wprojb, projb, out);
}

// Round 2
// 114.936 us; speedup vs baseline: 1.3139x; 1.3139x over previous
//
#include <hip/hip_runtime.h>
#include <hip/hip_bf16.h>
#include <stdint.h>

typedef __hip_bfloat16 bf16;
typedef __attribute__((ext_vector_type(8))) short bf16x8;
typedef __attribute__((ext_vector_type(4))) float f32x4;

#define MFMA16(a, b, c) __builtin_amdgcn_mfma_f32_16x16x32_bf16(a, b, c, 0, 0, 0)

__device__ __forceinline__ void gl_lds16(const void* g, void* l) {
  __builtin_amdgcn_global_load_lds(
      (const __attribute__((address_space(1))) uint32_t*)g,
      (__attribute__((address_space(3))) uint32_t*)l, 16, 0, 0);
}

// ---------------- cast fp32 -> bf16 (vectorized) ----------------
struct alignas(8) bf16x4s { bf16 a, b, c, d; };

__global__ void k_cast(const float* __restrict__ src, bf16* __restrict__ dst, int n4) {
  int i = blockIdx.x * 256 + threadIdx.x;
  if (i >= n4) return;
  float4 v = ((const float4*)src)[i];
  bf16x4s o{__float2bfloat16(v.x), __float2bfloat16(v.y),
            __float2bfloat16(v.z), __float2bfloat16(v.w)};
  ((bf16x4s*)dst)[i] = o;
}

// ---------------- axial RoPE cos/sin table: [pos(1024)][pair(32)] ----------------
__global__ void k_cis(float* __restrict__ cosT, float* __restrict__ sinT) {
  int i = blockIdx.x * 256 + threadIdx.x;  // 32768
  int pos = i >> 5, p = i & 31;
  int j = p & 15;
  float t = (p < 16) ? (float)(pos & 31) : (float)(pos >> 5);  // t_x = l%32, t_y = l/32
  float f = powf(10000.0f, -(float)j / 16.0f);
  float ang = t * f;
  float sv, cv;
  sincosf(ang, &sv, &cv);
  cosT[i] = cv;
  sinT[i] = sv;
}

// ---------------- shared 128x128-tile GEMM mainloop (K=768, B^T layout) -------
// C = A(M x 768) * Bt(N x 768)^T ; 256 threads = 4 waves (2x2), 64x64 per wave.
__device__ __forceinline__ void gemm128_loop(const bf16* __restrict__ A,
                                             const bf16* __restrict__ Bt,
                                             int m0, int n0, bf16* ldsA, bf16* ldsB,
                                             f32x4 acc[4][4]) {
  const int tid = threadIdx.x;
  const int lane = tid & 63, w = tid >> 6;
  const int wm = w >> 1, wn = w & 1;
  const int lr = lane & 15, lg = lane >> 4;
  for (int kt = 0; kt < 768; kt += 32) {
#pragma unroll
    for (int c = 0; c < 2; ++c) {
      const int off = c * 4096 + w * 1024 + lane * 16;  // byte in 8KB tile [128][32]bf16
      const int row = off >> 6, colb = off & 63;
      gl_lds16((const char*)A + ((size_t)(m0 + row) * 768 + kt) * 2 + colb,
               (char*)ldsA + c * 4096 + w * 1024);
      gl_lds16((const char*)Bt + ((size_t)(n0 + row) * 768 + kt) * 2 + colb,
               (char*)ldsB + c * 4096 + w * 1024);
    }
    __syncthreads();
    bf16x8 af[4], bf_[4];
#pragma unroll
    for (int f = 0; f < 4; ++f) {
      af[f] = *(const bf16x8*)((const char*)ldsA + (wm * 64 + f * 16 + lr) * 64 + lg * 16);
      bf_[f] = *(const bf16x8*)((const char*)ldsB + (wn * 64 + f * 16 + lr) * 64 + lg * 16);
    }
#pragma unroll
    for (int fm = 0; fm < 4; ++fm)
#pragma unroll
      for (int fn = 0; fn < 4; ++fn)
        acc[fm][fn] = MFMA16(af[fm], bf_[fn], acc[fm][fn]);
    __syncthreads();
  }
}

// ---------------- QKV GEMM + bias + RoPE epilogue ----------------
// writes Qb,Kb: [bn][pos][d] bf16 (RoPE'd); VbT: [bn][d][pos] bf16 (transposed)
__global__ __launch_bounds__(256, 2) void k_qkv(
    const bf16* __restrict__ xb, const bf16* __restrict__ wb, const float* __restrict__ qkvb,
    const float* __restrict__ cosT, const float* __restrict__ sinT,
    bf16* __restrict__ Qb, bf16* __restrict__ Kb, bf16* __restrict__ VbT) {
  __shared__ __align__(16) bf16 ldsA[128 * 32];
  __shared__ __align__(16) bf16 ldsB[128 * 32];
  const int m0 = (blockIdx.x & 31) * 128, n0 = (blockIdx.x >> 5) * 128;
  f32x4 acc[4][4] = {};
  gemm128_loop(xb, wb, m0, n0, ldsA, ldsB, acc);
  const int lane = threadIdx.x & 63, w = threadIdx.x >> 6;
  const int wm = w >> 1, wn = w & 1, lr = lane & 15, lg = lane >> 4;
#pragma unroll
  for (int fm = 0; fm < 4; ++fm) {
#pragma unroll
    for (int fn = 0; fn < 4; ++fn) {
      const int n = n0 + wn * 64 + fn * 16 + lr;  // 0..2303
      const int sect = n / 768;                   // 0=q 1=k 2=v (uniform per wave)
      const int cn = n - sect * 768;
      const int head = cn >> 6, d = cn & 63;
      const float bias = qkvb[n];
      const int p = d >> 1;
#pragma unroll
      for (int r = 0; r < 4; ++r) {
        const int m = m0 + wm * 64 + fm * 16 + lg * 4 + r;
        const int bb = m >> 10, pos = m & 1023;
        float val = acc[fm][fn][r] + bias;
        const float partner = __shfl_xor(val, 1);  // pair channel (d^1) lives in lane^1
        if (sect < 2) {
          const float cv = cosT[pos * 32 + p], sv = sinT[pos * 32 + p];
          val = (d & 1) ? (val * cv + partner * sv) : (val * cv - partner * sv);
        }
        const bf16 o = __float2bfloat16(val);
        const size_t base = (size_t)(bb * 12 + head) * 65536;
        if (sect == 0)      Qb[base + (size_t)pos * 64 + d] = o;
        else if (sect == 1) Kb[base + (size_t)pos * 64 + d] = o;
        else                VbT[base + (size_t)d * 1024 + pos] = o;
      }
    }
  }
}

// ---------------- decomposed rel-pos bias tables via MFMA (no LDS) ----------------
// relh[bn][l][kh] = sum_d q[bn][l][d] * rel_pos_h[qh-kh+31][d]   (l=(qh,qw))
// relw[bn][l][kw] = sum_d q[bn][l][d] * rel_pos_w[qw-kw+31][d]
// One wave = one (bn, isW, rc) instance = 32x32x64 GEMM = 8 MFMAs, frags straight
// from global (Q already bf16; rel_pos fp32 -> bf16 in-register). No LDS, no barriers.
__global__ __launch_bounds__(256) void k_relbias(
    const bf16* __restrict__ Qb, const float* __restrict__ relph,
    const float* __restrict__ relpw, float* __restrict__ relh,
    float* __restrict__ relw) {
  const int bid = blockIdx.x;          // 768 = 48 bn * 2 part * 8 rc-groups
  const int bn = bid >> 4;
  const int rem = bid & 15;
  const bool isW = (rem >> 3) != 0;
  const int w = threadIdx.x >> 6;
  const int rc = (rem & 7) * 4 + w;    // 0..31
  const int lane = threadIdx.x & 63;
  const int lr = lane & 15, lg = lane >> 4;
  const float* __restrict__ relp = isW ? relpw : relph;

  bf16x8 af[2][2];   // A = Q rows; [m-block][k-step]
#pragma unroll
  for (int mb = 0; mb < 2; ++mb) {
    const int m = mb * 16 + lr;
    const int l = isW ? (m * 32 + rc) : (rc * 32 + m);
    const bf16* ap = Qb + (size_t)bn * 65536 + (size_t)l * 64 + lg * 8;
#pragma unroll
    for (int ks = 0; ks < 2; ++ks) af[mb][ks] = *(const bf16x8*)(ap + ks * 32);
  }
  bf16x8 bfr[2][2];  // B = rel_pos rows (fp32 -> bf16); [n-block][k-step]
#pragma unroll
  for (int nb = 0; nb < 2; ++nb) {
    const int n = nb * 16 + lr;
    const float* bp = relp + (size_t)(31 + rc - n) * 64 + lg * 8;
#pragma unroll
    for (int ks = 0; ks < 2; ++ks) {
      const float4 f0 = *(const float4*)(bp + ks * 32);
      const float4 f1 = *(const float4*)(bp + ks * 32 + 4);
      bf16x8 t;
      ((bf16*)&t)[0] = __float2bfloat16(f0.x);
      ((bf16*)&t)[1] = __float2bfloat16(f0.y);
      ((bf16*)&t)[2] = __float2bfloat16(f0.z);
      ((bf16*)&t)[3] = __float2bfloat16(f0.w);
      ((bf16*)&t)[4] = __float2bfloat16(f1.x);
      ((bf16*)&t)[5] = __float2bfloat16(f1.y);
      ((bf16*)&t)[6] = __float2bfloat16(f1.z);
      ((bf16*)&t)[7] = __float2bfloat16(f1.w);
      bfr[nb][ks] = t;
    }
  }
  f32x4 acc[2][2] = {};
#pragma unroll
  for (int ks = 0; ks < 2; ++ks)
#pragma unroll
    for (int mb = 0; mb < 2; ++mb)
#pragma unroll
      for (int nb = 0; nb < 2; ++nb)
        acc[mb][nb] = MFMA16(af[mb][ks], bfr[nb][ks], acc[mb][nb]);
  float* __restrict__ dst = isW ? relw : relh;
#pragma unroll
  for (int mb = 0; mb < 2; ++mb)
#pragma unroll
    for (int nb = 0; nb < 2; ++nb)
#pragma unroll
      for (int r = 0; r < 4; ++r) {
        const int mo = mb * 16 + lg * 4 + r;
        const int n = nb * 16 + lr;
        const int l = isW ? (mo * 32 + rc) : (rc * 32 + mo);
        dst[(size_t)bn * 32768 + (size_t)l * 32 + n] = acc[mb][nb][r];
      }
}

// ---------------- flash attention: one block = (bn, 64-row q-tile) ----------------
__global__ __launch_bounds__(256, 2) void k_attn(
    const bf16* __restrict__ Qb, const bf16* __restrict__ Kb, const bf16* __restrict__ VbT,
    const float* __restrict__ relh, const float* __restrict__ relw, bf16* __restrict__ attno) {
  __shared__ __align__(16) bf16 Kt[64 * 64];      // [key][ch], XOR-swizzled rows
  __shared__ __align__(16) bf16 Vt[64 * 64];      // [d][key] (V^T), XOR-swizzled rows
  __shared__ __align__(16) float bH[64 * 33];     // rel_h slice, padded
  __shared__ __align__(16) bf16 Pl[4][16 * 64];   // per-wave P transpose buffer, swizzled
  const int blk = blockIdx.x;                     // 768 = 48 bn * 16 qtiles
  const int bn = blk >> 4, qt = blk & 15;
  const int b = bn / 12, head = bn - b * 12;
  const int tid = threadIdx.x;
  const int lane = tid & 63, w = tid >> 6;
  const int lr = lane & 15, lg = lane >> 4;
  const size_t qkvbase = (size_t)bn * 65536;

  {  // stage bias-H rows for this q-tile
    const int r = tid >> 2, q8 = (tid & 3) * 8;
    const float* src = relh + (size_t)bn * 32768 + (size_t)(qt * 64 + r) * 32 + q8;
#pragma unroll
    for (int jj = 0; jj < 8; ++jj) bH[r * 33 + q8 + jj] = src[jj];
  }
  const int qrow_g = qt * 64 + w * 16 + lr;
  float bw[2][4];  // bias-W values this lane will need: kw = s1*16 + lg*4 + r
  {
    const float* rw = relw + (size_t)bn * 32768 + (size_t)qrow_g * 32;
#pragma unroll
    for (int s1 = 0; s1 < 2; ++s1)
#pragma unroll
      for (int r = 0; r < 4; ++r) bw[s1][r] = rw[s1 * 16 + lg * 4 + r];
  }
  bf16x8 qf[2];  // Q fragment (B-operand of swapped QK^T), kept in regs
  {
    const char* qp = (const char*)(Qb + qkvbase + (size_t)qrow_g * 64);
    qf[0] = *(const bf16x8*)(qp + lg * 16);
    qf[1] = *(const bf16x8*)(qp + 64 + lg * 16);
  }
  f32x4 oacc[4] = {};  // D rows = q-rows (lg*4+r), cols = d (dblk*16+lr)
  float mrun = -1e30f, lrun = 0.0f;

  for (int kt = 0; kt < 16; ++kt) {
    // stage K-tile and V^T-tile, pre-swizzling the GLOBAL source (rule #21)
#pragma unroll
    for (int c = 0; c < 2; ++c) {
      const int off = c * 4096 + w * 1024 + lane * 16;
      const int row = off >> 7;
      const int loff = off ^ ((row & 7) << 4);
      gl_lds16((const char*)Kb + (qkvbase + (size_t)kt * 4096) * 2 + loff,
               (char*)Kt + c * 4096 + w * 1024);
      gl_lds16((const char*)VbT + (qkvbase + (size_t)row * 1024 + (size_t)kt * 64) * 2 + (loff & 127),
               (char*)Vt + c * 4096 + w * 1024);
    }
    __syncthreads();
    // swapped QK^T: S^T[key][qrow]; lane holds q-row lr, keys s*16 + lg*4 + r
    f32x4 sa[4];
    const int sw = (lr & 7) << 4;
#pragma unroll
    for (int s = 0; s < 4; ++s) {
      const int krow = s * 16 + lr;
      bf16x8 k0 = *(const bf16x8*)((const char*)Kt + ((krow * 128 + lg * 16) ^ sw));
      bf16x8 k1 = *(const bf16x8*)((const char*)Kt + ((krow * 128 + 64 + lg * 16) ^ sw));
      f32x4 z = {};
      z = MFMA16(k0, qf[0], z);
      z = MFMA16(k1, qf[1], z);
      sa[s] = z;
    }
    // scores = S*scale + rel_h[qrow][kh] + rel_w[qrow][kw]
    const float bh0 = bH[(w * 16 + lr) * 33 + 2 * kt];
    const float bh1 = bH[(w * 16 + lr) * 33 + 2 * kt + 1];
    float sc[16];
    float mt = -1e30f;
#pragma unroll
    for (int s = 0; s < 4; ++s) {
      const float bh = (s < 2) ? bh0 : bh1;
#pragma unroll
      for (int r = 0; r < 4; ++r) {
        const float v = sa[s][r] * 0.125f + bh + bw[s & 1][r];
        sc[s * 4 + r] = v;
        mt = fmaxf(mt, v);
      }
    }
    mt = fmaxf(mt, __shfl_xor(mt, 16));
    mt = fmaxf(mt, __shfl_xor(mt, 32));
    const float mnew = fmaxf(mrun, mt);
    const float alpha = __expf(mrun - mnew);
    float ps = 0.0f;
    short4 pk[4];
#pragma unroll
    for (int s = 0; s < 4; ++s) {
#pragma unroll
      for (int r = 0; r < 4; ++r) {
        const float p = __expf(sc[s * 4 + r] - mnew);
        ps += p;
        ((bf16*)&pk[s])[r] = __float2bfloat16(p);
      }
    }
    ps += __shfl_xor(ps, 16);
    ps += __shfl_xor(ps, 32);
    lrun = lrun * alpha + ps;
    mrun = mnew;
    // P -> LDS (transpose for PV A-operand), same XOR swizzle on write & read
#pragma unroll
    for (int s = 0; s < 4; ++s) {
      int byteoff = (lr * 128 + s * 32 + lg * 8) ^ sw;
      *(short4*)((char*)Pl[w] + byteoff) = pk[s];
    }
    // rescale running output by alpha (per D-row = q-row lg*4+r)
#pragma unroll
    for (int r = 0; r < 4; ++r) {
      const float ar = __shfl(alpha, lg * 4 + r);
#pragma unroll
      for (int dblk = 0; dblk < 4; ++dblk) oacc[dblk][r] *= ar;
    }
    asm volatile("s_waitcnt lgkmcnt(0)" ::: "memory");  // P writes visible to wave
    // PV: out += P(16 x 64keys) * V(64keys x 64d)
#pragma unroll
    for (int kh = 0; kh < 2; ++kh) {
      const int abyte = (lr * 128 + kh * 64 + lg * 16) ^ sw;
      const bf16x8 pa = *(const bf16x8*)((const char*)Pl[w] + abyte);
#pragma unroll
      for (int dblk = 0; dblk < 4; ++dblk) {
        const int vrow = dblk * 16 + lr;
        const bf16x8 vb = *(const bf16x8*)((const char*)Vt + ((vrow * 128 + kh * 64 + lg * 16) ^ sw));
        oacc[dblk] = MFMA16(pa, vb, oacc[dblk]);
      }
    }
    __syncthreads();
  }
  // normalize + store to (B, L, nh*hd) bf16 for proj GEMM
#pragma unroll
  for (int r = 0; r < 4; ++r) {
    const float lsum = __shfl(lrun, lg * 4 + r);
    const float inv = 1.0f / lsum;
    const int qg = qt * 64 + w * 16 + lg * 4 + r;
#pragma unroll
    for (int dblk = 0; dblk < 4; ++dblk) {
      attno[((size_t)b * 1024 + qg) * 768 + head * 64 + dblk * 16 + lr] =
          __float2bfloat16(oacc[dblk][r] * inv);
    }
  }
}

// ---------------- output projection GEMM + bias (fp32 out) ----------------
__global__ __launch_bounds__(256, 2) void k_proj(
    const bf16* __restrict__ attno, const bf16* __restrict__ pwb,
    const float* __restrict__ projb, float* __restrict__ out) {
  __shared__ __align__(16) bf16 ldsA[128 * 32];
  __shared__ __align__(16) bf16 ldsB[128 * 32];
  const int m0 = (blockIdx.x & 31) * 128, n0 = (blockIdx.x >> 5) * 128;
  f32x4 acc[4][4] = {};
  gemm128_loop(attno, pwb, m0, n0, ldsA, ldsB, acc);
  const int lane = threadIdx.x & 63, w = threadIdx.x >> 6;
  const int wm = w >> 1, wn = w & 1, lr = lane & 15, lg = lane >> 4;
#pragma unroll
  for (int fm = 0; fm < 4; ++fm) {
#pragma unroll
    for (int fn = 0; fn < 4; ++fn) {
      const int n = n0 + wn * 64 + fn * 16 + lr;
      const float bias = projb[n];
#pragma unroll
      for (int r = 0; r < 4; ++r) {
        const int m = m0 + wm * 64 + fm * 16 + lg * 4 + r;
        out[(size_t)m * 768 + n] = acc[fm][fn][r] + bias;
      }
    }
  }
}

// ---------------- launch ----------------
extern "C" void kernel_launch(void* const* d_in, const int* in_sizes, int n_in,
                              void* d_out, int out_size, void* d_ws, size_t ws_size,
                              hipStream_t stream) {
  const float* x     = (const float*)d_in[0];
  const float* qkvw  = (const float*)d_in[1];
  const float* qkvb  = (const float*)d_in[2];
  const float* projw = (const float*)d_in[3];
  const float* projb = (const float*)d_in[4];
  const float* relph = (const float*)d_in[5];
  const float* relpw = (const float*)d_in[6];
  float* out = (float*)d_out;
  char* ws = (char*)d_ws;

  bf16*  xb     = (bf16*)(ws);              // 6,291,456 B
  bf16*  wqkvb  = (bf16*)(ws + 6291456);    // 3,538,944
  bf16*  wprojb = (bf16*)(ws + 9830400);    // 1,179,648
  float* cosT   = (float*)(ws + 11010048);  // 131,072
  float* sinT   = (float*)(ws + 11141120);  // 131,072
  bf16*  Qb     = (bf16*)(ws + 11272192);   // 6,291,456
  bf16*  Kb     = (bf16*)(ws + 17563648);   // 6,291,456
  bf16*  VbT    = (bf16*)(ws + 23855104);   // 6,291,456
  float* relh   = (float*)(ws + 30146560);  // 6,291,456
  float* relw   = (float*)(ws + 36438016);  // 6,291,456
  bf16*  attno  = (bf16*)(ws + 42729472);   // 6,291,456 -> ends 49,020,928

  k_cast<<<3072, 256, 0, stream>>>(x, xb, 786432);
  k_cast<<<1728, 256, 0, stream>>>(qkvw, wqkvb, 442368);
  k_cast<<<576, 256, 0, stream>>>(projw, wprojb, 147456);
  k_cis<<<128, 256, 0, stream>>>(cosT, sinT);
  k_qkv<<<576, 256, 0, stream>>>(xb, wqkvb, qkvb, cosT, sinT, Qb, Kb, VbT);
  k_relbias<<<768, 256, 0, stream>>>(Qb, relph, relpw, relh, relw);
  k_attn<<<768, 256, 0, stream>>>(Qb, Kb, VbT, relh, relw, attno);
  k_proj<<<192, 256, 0, stream>>>(attno, wprojb, projb, out);
}

// Round 3
// 108.550 us; speedup vs baseline: 1.3912x; 1.0588x over previous
//
#include <hip/hip_runtime.h>
#include <hip/hip_bf16.h>
#include <stdint.h>

typedef __hip_bfloat16 bf16;
typedef __attribute__((ext_vector_type(8))) short bf16x8;
typedef __attribute__((ext_vector_type(4))) float f32x4;

#define MFMA16(a, b, c) __builtin_amdgcn_mfma_f32_16x16x32_bf16(a, b, c, 0, 0, 0)

__device__ __forceinline__ void gl_lds16(const void* g, void* l) {
  __builtin_amdgcn_global_load_lds(
      (const __attribute__((address_space(1))) uint32_t*)g,
      (__attribute__((address_space(3))) uint32_t*)l, 16, 0, 0);
}

// ---------------- fused prep: casts + RoPE table (one launch) ----------------
struct alignas(8) bf16x4s { bf16 a, b, c, d; };

__device__ __forceinline__ void cast4(const float* __restrict__ src,
                                      bf16* __restrict__ dst, int i) {
  float4 v = ((const float4*)src)[i];
  bf16x4s o{__float2bfloat16(v.x), __float2bfloat16(v.y),
            __float2bfloat16(v.z), __float2bfloat16(v.w)};
  ((bf16x4s*)dst)[i] = o;
}

__global__ void k_prep(const float* __restrict__ x, const float* __restrict__ qkvw,
                       const float* __restrict__ projw, bf16* __restrict__ xb,
                       bf16* __restrict__ wqkvb, bf16* __restrict__ wprojb,
                       float* __restrict__ cosT, float* __restrict__ sinT) {
  const int bid = blockIdx.x, tid = threadIdx.x;
  if (bid < 3072) {            // x: 786432 float4
    cast4(x, xb, bid * 256 + tid);
  } else if (bid < 4800) {     // qkv_w: 442368 float4
    cast4(qkvw, wqkvb, (bid - 3072) * 256 + tid);
  } else if (bid < 5376) {     // proj_w: 147456 float4
    cast4(projw, wprojb, (bid - 4800) * 256 + tid);
  } else {                     // cis table: 32768 entries
    const int i = (bid - 5376) * 256 + tid;
    const int pos = i >> 5, p = i & 31;
    const int j = p & 15;
    const float t = (p < 16) ? (float)(pos & 31) : (float)(pos >> 5);
    const float f = powf(10000.0f, -(float)j / 16.0f);
    float sv, cv;
    sincosf(t * f, &sv, &cv);
    cosT[i] = cv;
    sinT[i] = sv;
  }
}

// ------- 128x128-tile GEMM mainloop, 2-phase prefetch (K=768, B^T layout) -------
// C = A(M x 768) * Bt(N x 768)^T ; 256 threads = 4 waves (2x2), 64x64 per wave.
// ldsA/ldsB are [2][128*32] double buffers. STAGE(t+1) issued BEFORE compute(t);
// __syncthreads() drains vmcnt(0) AFTER compute -> load latency hidden (T3 min-2-phase).
__device__ __forceinline__ void gemm128_loop(const bf16* __restrict__ A,
                                             const bf16* __restrict__ Bt,
                                             int m0, int n0, bf16* ldsA, bf16* ldsB,
                                             f32x4 acc[4][4]) {
  const int tid = threadIdx.x;
  const int lane = tid & 63, w = tid >> 6;
  const int wm = w >> 1, wn = w & 1;
  const int lr = lane & 15, lg = lane >> 4;
  const int off0 = w * 1024 + lane * 16;

  auto stage = [&](int kt, int buf) {
#pragma unroll
    for (int c = 0; c < 2; ++c) {
      const int o = c * 4096 + off0;           // byte in 8KB tile [128][32]bf16
      const int row = o >> 6, colb = o & 63;
      gl_lds16((const char*)A + ((size_t)(m0 + row) * 768 + kt) * 2 + colb,
               (char*)ldsA + buf * 8192 + c * 4096 + w * 1024);
      gl_lds16((const char*)Bt + ((size_t)(n0 + row) * 768 + kt) * 2 + colb,
               (char*)ldsB + buf * 8192 + c * 4096 + w * 1024);
    }
  };

  stage(0, 0);
  __syncthreads();  // drains vmcnt(0)
  int cur = 0;
  for (int ki = 0; ki < 24; ++ki) {
    if (ki + 1 < 24) stage((ki + 1) * 32, cur ^ 1);  // prefetch next tile
    const char* baseA = (const char*)ldsA + cur * 8192;
    const char* baseB = (const char*)ldsB + cur * 8192;
    bf16x8 af[4], bf_[4];
#pragma unroll
    for (int f = 0; f < 4; ++f) {
      af[f] = *(const bf16x8*)(baseA + (wm * 64 + f * 16 + lr) * 64 + lg * 16);
      bf_[f] = *(const bf16x8*)(baseB + (wn * 64 + f * 16 + lr) * 64 + lg * 16);
    }
#pragma unroll
    for (int fm = 0; fm < 4; ++fm)
#pragma unroll
      for (int fn = 0; fn < 4; ++fn)
        acc[fm][fn] = MFMA16(af[fm], bf_[fn], acc[fm][fn]);
    __syncthreads();  // drains vmcnt(0) after compute
    cur ^= 1;
  }
}

// ---------------- QKV GEMM + bias + RoPE epilogue ----------------
// writes Qb,Kb: [bn][pos][d] bf16 (RoPE'd); VbT: [bn][d][pos] bf16 (transposed)
__global__ __launch_bounds__(256, 3) void k_qkv(
    const bf16* __restrict__ xb, const bf16* __restrict__ wb, const float* __restrict__ qkvb,
    const float* __restrict__ cosT, const float* __restrict__ sinT,
    bf16* __restrict__ Qb, bf16* __restrict__ Kb, bf16* __restrict__ VbT) {
  __shared__ __align__(16) bf16 ldsA[2][128 * 32];
  __shared__ __align__(16) bf16 ldsB[2][128 * 32];
  const int m0 = (blockIdx.x & 31) * 128, n0 = (blockIdx.x >> 5) * 128;
  f32x4 acc[4][4] = {};
  gemm128_loop(xb, wb, m0, n0, &ldsA[0][0], &ldsB[0][0], acc);
  const int lane = threadIdx.x & 63, w = threadIdx.x >> 6;
  const int wm = w >> 1, wn = w & 1, lr = lane & 15, lg = lane >> 4;
#pragma unroll
  for (int fm = 0; fm < 4; ++fm) {
#pragma unroll
    for (int fn = 0; fn < 4; ++fn) {
      const int n = n0 + wn * 64 + fn * 16 + lr;  // 0..2303
      const int sect = n / 768;                   // 0=q 1=k 2=v (uniform per wave)
      const int cn = n - sect * 768;
      const int head = cn >> 6, d = cn & 63;
      const float bias = qkvb[n];
      const int p = d >> 1;
#pragma unroll
      for (int r = 0; r < 4; ++r) {
        const int m = m0 + wm * 64 + fm * 16 + lg * 4 + r;
        const int bb = m >> 10, pos = m & 1023;
        float val = acc[fm][fn][r] + bias;
        const float partner = __shfl_xor(val, 1);  // pair channel (d^1) lives in lane^1
        if (sect < 2) {
          const float cv = cosT[pos * 32 + p], sv = sinT[pos * 32 + p];
          val = (d & 1) ? (val * cv + partner * sv) : (val * cv - partner * sv);
        }
        const bf16 o = __float2bfloat16(val);
        const size_t base = (size_t)(bb * 12 + head) * 65536;
        if (sect == 0)      Qb[base + (size_t)pos * 64 + d] = o;
        else if (sect == 1) Kb[base + (size_t)pos * 64 + d] = o;
        else                VbT[base + (size_t)d * 1024 + pos] = o;
      }
    }
  }
}

// ---------------- decomposed rel-pos bias tables via MFMA (no LDS) ----------------
__global__ __launch_bounds__(256) void k_relbias(
    const bf16* __restrict__ Qb, const float* __restrict__ relph,
    const float* __restrict__ relpw, float* __restrict__ relh,
    float* __restrict__ relw) {
  const int bid = blockIdx.x;          // 768 = 48 bn * 2 part * 8 rc-groups
  const int bn = bid >> 4;
  const int rem = bid & 15;
  const bool isW = (rem >> 3) != 0;
  const int w = threadIdx.x >> 6;
  const int rc = (rem & 7) * 4 + w;    // 0..31
  const int lane = threadIdx.x & 63;
  const int lr = lane & 15, lg = lane >> 4;
  const float* __restrict__ relp = isW ? relpw : relph;

  bf16x8 af[2][2];   // A = Q rows; [m-block][k-step]
#pragma unroll
  for (int mb = 0; mb < 2; ++mb) {
    const int m = mb * 16 + lr;
    const int l = isW ? (m * 32 + rc) : (rc * 32 + m);
    const bf16* ap = Qb + (size_t)bn * 65536 + (size_t)l * 64 + lg * 8;
#pragma unroll
    for (int ks = 0; ks < 2; ++ks) af[mb][ks] = *(const bf16x8*)(ap + ks * 32);
  }
  bf16x8 bfr[2][2];  // B = rel_pos rows (fp32 -> bf16); [n-block][k-step]
#pragma unroll
  for (int nb = 0; nb < 2; ++nb) {
    const int n = nb * 16 + lr;
    const float* bp = relp + (size_t)(31 + rc - n) * 64 + lg * 8;
#pragma unroll
    for (int ks = 0; ks < 2; ++ks) {
      const float4 f0 = *(const float4*)(bp + ks * 32);
      const float4 f1 = *(const float4*)(bp + ks * 32 + 4);
      bf16x8 t;
      ((bf16*)&t)[0] = __float2bfloat16(f0.x);
      ((bf16*)&t)[1] = __float2bfloat16(f0.y);
      ((bf16*)&t)[2] = __float2bfloat16(f0.z);
      ((bf16*)&t)[3] = __float2bfloat16(f0.w);
      ((bf16*)&t)[4] = __float2bfloat16(f1.x);
      ((bf16*)&t)[5] = __float2bfloat16(f1.y);
      ((bf16*)&t)[6] = __float2bfloat16(f1.z);
      ((bf16*)&t)[7] = __float2bfloat16(f1.w);
      bfr[nb][ks] = t;
    }
  }
  f32x4 acc[2][2] = {};
#pragma unroll
  for (int ks = 0; ks < 2; ++ks)
#pragma unroll
    for (int mb = 0; mb < 2; ++mb)
#pragma unroll
      for (int nb = 0; nb < 2; ++nb)
        acc[mb][nb] = MFMA16(af[mb][ks], bfr[nb][ks], acc[mb][nb]);
  float* __restrict__ dst = isW ? relw : relh;
#pragma unroll
  for (int mb = 0; mb < 2; ++mb)
#pragma unroll
    for (int nb = 0; nb < 2; ++nb)
#pragma unroll
      for (int r = 0; r < 4; ++r) {
        const int mo = mb * 16 + lg * 4 + r;
        const int n = nb * 16 + lr;
        const int l = isW ? (mo * 32 + rc) : (rc * 32 + mo);
        dst[(size_t)bn * 32768 + (size_t)l * 32 + n] = acc[mb][nb][r];
      }
}

// ---------------- flash attention: one block = (bn, 64-row q-tile) ----------------
// K/V double-buffered with 2-phase prefetch (T3): stage(kt+1) before compute(kt).
__global__ __launch_bounds__(256, 3) void k_attn(
    const bf16* __restrict__ Qb, const bf16* __restrict__ Kb, const bf16* __restrict__ VbT,
    const float* __restrict__ relh, const float* __restrict__ relw, bf16* __restrict__ attno) {
  __shared__ __align__(16) bf16 Kt[2][64 * 64];   // [key][ch], XOR-swizzled rows
  __shared__ __align__(16) bf16 Vt[2][64 * 64];   // [d][key] (V^T), XOR-swizzled rows
  __shared__ __align__(16) float bH[64 * 33];     // rel_h slice, padded
  __shared__ __align__(16) bf16 Pl[4][16 * 64];   // per-wave P transpose buffer, swizzled
  const int blk = blockIdx.x;                     // 768 = 48 bn * 16 qtiles
  const int bn = blk >> 4, qt = blk & 15;
  const int b = bn / 12, head = bn - b * 12;
  const int tid = threadIdx.x;
  const int lane = tid & 63, w = tid >> 6;
  const int lr = lane & 15, lg = lane >> 4;
  const size_t qkvbase = (size_t)bn * 65536;

  auto stageKV = [&](int kt, int buf) {
#pragma unroll
    for (int c = 0; c < 2; ++c) {
      const int off = c * 4096 + w * 1024 + lane * 16;
      const int row = off >> 7;
      const int loff = off ^ ((row & 7) << 4);  // pre-swizzled global source (rule #21)
      gl_lds16((const char*)Kb + (qkvbase + (size_t)kt * 4096) * 2 + loff,
               (char*)Kt + buf * 8192 + c * 4096 + w * 1024);
      gl_lds16((const char*)VbT + (qkvbase + (size_t)row * 1024 + (size_t)kt * 64) * 2 + (loff & 127),
               (char*)Vt + buf * 8192 + c * 4096 + w * 1024);
    }
  };

  stageKV(0, 0);
  {  // stage bias-H rows for this q-tile (overlaps with K/V load latency)
    const int r = tid >> 2, q8 = (tid & 3) * 8;
    const float* src = relh + (size_t)bn * 32768 + (size_t)(qt * 64 + r) * 32 + q8;
#pragma unroll
    for (int jj = 0; jj < 8; ++jj) bH[r * 33 + q8 + jj] = src[jj];
  }
  const int qrow_g = qt * 64 + w * 16 + lr;
  float bw[2][4];  // bias-W values this lane will need: kw = s1*16 + lg*4 + r
  {
    const float* rw = relw + (size_t)bn * 32768 + (size_t)qrow_g * 32;
#pragma unroll
    for (int s1 = 0; s1 < 2; ++s1)
#pragma unroll
      for (int r = 0; r < 4; ++r) bw[s1][r] = rw[s1 * 16 + lg * 4 + r];
  }
  bf16x8 qf[2];  // Q fragment (B-operand of swapped QK^T), kept in regs
  {
    const char* qp = (const char*)(Qb + qkvbase + (size_t)qrow_g * 64);
    qf[0] = *(const bf16x8*)(qp + lg * 16);
    qf[1] = *(const bf16x8*)(qp + 64 + lg * 16);
  }
  f32x4 oacc[4] = {};  // D rows = q-rows (lg*4+r), cols = d (dblk*16+lr)
  float mrun = -1e30f, lrun = 0.0f;
  __syncthreads();  // drains vmcnt(0): Kt[0]/Vt[0] ready
  int cur = 0;

  for (int kt = 0; kt < 16; ++kt) {
    if (kt + 1 < 16) stageKV(kt + 1, cur ^ 1);  // prefetch next K/V tile
    const char* Ktc = (const char*)Kt + cur * 8192;
    const char* Vtc = (const char*)Vt + cur * 8192;
    // swapped QK^T: S^T[key][qrow]; lane holds q-row lr, keys s*16 + lg*4 + r
    f32x4 sa[4];
    const int sw = (lr & 7) << 4;
#pragma unroll
    for (int s = 0; s < 4; ++s) {
      const int krow = s * 16 + lr;
      bf16x8 k0 = *(const bf16x8*)(Ktc + ((krow * 128 + lg * 16) ^ sw));
      bf16x8 k1 = *(const bf16x8*)(Ktc + ((krow * 128 + 64 + lg * 16) ^ sw));
      f32x4 z = {};
      z = MFMA16(k0, qf[0], z);
      z = MFMA16(k1, qf[1], z);
      sa[s] = z;
    }
    // scores = S*scale + rel_h[qrow][kh] + rel_w[qrow][kw]
    const float bh0 = bH[(w * 16 + lr) * 33 + 2 * kt];
    const float bh1 = bH[(w * 16 + lr) * 33 + 2 * kt + 1];
    float sc[16];
    float mt = -1e30f;
#pragma unroll
    for (int s = 0; s < 4; ++s) {
      const float bh = (s < 2) ? bh0 : bh1;
#pragma unroll
      for (int r = 0; r < 4; ++r) {
        const float v = sa[s][r] * 0.125f + bh + bw[s & 1][r];
        sc[s * 4 + r] = v;
        mt = fmaxf(mt, v);
      }
    }
    mt = fmaxf(mt, __shfl_xor(mt, 16));
    mt = fmaxf(mt, __shfl_xor(mt, 32));
    const float mnew = fmaxf(mrun, mt);
    const float alpha = __expf(mrun - mnew);
    float ps = 0.0f;
    short4 pk[4];
#pragma unroll
    for (int s = 0; s < 4; ++s) {
#pragma unroll
      for (int r = 0; r < 4; ++r) {
        const float p = __expf(sc[s * 4 + r] - mnew);
        ps += p;
        ((bf16*)&pk[s])[r] = __float2bfloat16(p);
      }
    }
    ps += __shfl_xor(ps, 16);
    ps += __shfl_xor(ps, 32);
    lrun = lrun * alpha + ps;
    mrun = mnew;
    // P -> LDS (transpose for PV A-operand), same XOR swizzle on write & read
#pragma unroll
    for (int s = 0; s < 4; ++s) {
      int byteoff = (lr * 128 + s * 32 + lg * 8) ^ sw;
      *(short4*)((char*)Pl[w] + byteoff) = pk[s];
    }
    // rescale running output by alpha (per D-row = q-row lg*4+r)
#pragma unroll
    for (int r = 0; r < 4; ++r) {
      const float ar = __shfl(alpha, lg * 4 + r);
#pragma unroll
      for (int dblk = 0; dblk < 4; ++dblk) oacc[dblk][r] *= ar;
    }
    asm volatile("s_waitcnt lgkmcnt(0)" ::: "memory");  // P writes visible to wave
    // PV: out += P(16 x 64keys) * V(64keys x 64d)
#pragma unroll
    for (int kh = 0; kh < 2; ++kh) {
      const int abyte = (lr * 128 + kh * 64 + lg * 16) ^ sw;
      const bf16x8 pa = *(const bf16x8*)((const char*)Pl[w] + abyte);
#pragma unroll
      for (int dblk = 0; dblk < 4; ++dblk) {
        const int vrow = dblk * 16 + lr;
        const bf16x8 vb = *(const bf16x8*)(Vtc + ((vrow * 128 + kh * 64 + lg * 16) ^ sw));
        oacc[dblk] = MFMA16(pa, vb, oacc[dblk]);
      }
    }
    __syncthreads();  // drains vmcnt(0) after compute; prefetched tile ready
    cur ^= 1;
  }
  // normalize + store to (B, L, nh*hd) bf16 for proj GEMM
#pragma unroll
  for (int r = 0; r < 4; ++r) {
    const float lsum = __shfl(lrun, lg * 4 + r);
    const float inv = 1.0f / lsum;
    const int qg = qt * 64 + w * 16 + lg * 4 + r;
#pragma unroll
    for (int dblk = 0; dblk < 4; ++dblk) {
      attno[((size_t)b * 1024 + qg) * 768 + head * 64 + dblk * 16 + lr] =
          __float2bfloat16(oacc[dblk][r] * inv);
    }
  }
}

// ---------------- output projection GEMM + bias (fp32 out) ----------------
__global__ __launch_bounds__(256, 3) void k_proj(
    const bf16* __restrict__ attno, const bf16* __restrict__ pwb,
    const float* __restrict__ projb, float* __restrict__ out) {
  __shared__ __align__(16) bf16 ldsA[2][128 * 32];
  __shared__ __align__(16) bf16 ldsB[2][128 * 32];
  const int m0 = (blockIdx.x & 31) * 128, n0 = (blockIdx.x >> 5) * 128;
  f32x4 acc[4][4] = {};
  gemm128_loop(attno, pwb, m0, n0, &ldsA[0][0], &ldsB[0][0], acc);
  const int lane = threadIdx.x & 63, w = threadIdx.x >> 6;
  const int wm = w >> 1, wn = w & 1, lr = lane & 15, lg = lane >> 4;
#pragma unroll
  for (int fm = 0; fm < 4; ++fm) {
#pragma unroll
    for (int fn = 0; fn < 4; ++fn) {
      const int n = n0 + wn * 64 + fn * 16 + lr;
      const float bias = projb[n];
#pragma unroll
      for (int r = 0; r < 4; ++r) {
        const int m = m0 + wm * 64 + fm * 16 + lg * 4 + r;
        out[(size_t)m * 768 + n] = acc[fm][fn][r] + bias;
      }
    }
  }
}

// ---------------- launch ----------------
extern "C" void kernel_launch(void* const* d_in, const int* in_sizes, int n_in,
                              void* d_out, int out_size, void* d_ws, size_t ws_size,
                              hipStream_t stream) {
  const float* x     = (const float*)d_in[0];
  const float* qkvw  = (const float*)d_in[1];
  const float* qkvb  = (const float*)d_in[2];
  const float* projw = (const float*)d_in[3];
  const float* projb = (const float*)d_in[4];
  const float* relph = (const float*)d_in[5];
  const float* relpw = (const float*)d_in[6];
  float* out = (float*)d_out;
  char* ws = (char*)d_ws;

  bf16*  xb     = (bf16*)(ws);              // 6,291,456 B
  bf16*  wqkvb  = (bf16*)(ws + 6291456);    // 3,538,944
  bf16*  wprojb = (bf16*)(ws + 9830400);    // 1,179,648
  float* cosT   = (float*)(ws + 11010048);  // 131,072
  float* sinT   = (float*)(ws + 11141120);  // 131,072
  bf16*  Qb     = (bf16*)(ws + 11272192);   // 6,291,456
  bf16*  Kb     = (bf16*)(ws + 17563648);   // 6,291,456
  bf16*  VbT    = (bf16*)(ws + 23855104);   // 6,291,456
  float* relh   = (float*)(ws + 30146560);  // 6,291,456
  float* relw   = (float*)(ws + 36438016);  // 6,291,456
  bf16*  attno  = (bf16*)(ws + 42729472);   // 6,291,456 -> ends 49,020,928

  k_prep<<<5504, 256, 0, stream>>>(x, qkvw, projw, xb, wqkvb, wprojb, cosT, sinT);
  k_qkv<<<576, 256, 0, stream>>>(xb, wqkvb, qkvb, cosT, sinT, Qb, Kb, VbT);
  k_relbias<<<768, 256, 0, stream>>>(Qb, relph, relpw, relh, relw);
  k_attn<<<768, 256, 0, stream>>>(Qb, Kb, VbT, relh, relw, attno);
  k_proj<<<192, 256, 0, stream>>>(attno, wprojb, projb, out);
}